// Round 2
// baseline (1634.238 us; speedup 1.0000x reference)
//
#include <hip/hip_runtime.h>

#define Bsz 256
#define Tsz 512
#define Isz 64
#define Hsz 128
#define G4  512   // 4*H

typedef _Float16 f16;
typedef _Float16 f16x8 __attribute__((ext_vector_type(8)));
typedef _Float16 f16x4 __attribute__((ext_vector_type(4)));
typedef float floatx4 __attribute__((ext_vector_type(4)));

#define MFMA(A, B, C) __builtin_amdgcn_mfma_f32_16x16x32_f16((A), (B), (C), 0, 0, 0)

__device__ __forceinline__ float sigm_f(float x) {
  float e = __builtin_amdgcn_exp2f(x * -1.4426950408889634f);
  return __builtin_amdgcn_rcpf(1.0f + e);
}
__device__ __forceinline__ float tanh_f(float x) {
  float e = __builtin_amdgcn_exp2f(x * -2.8853900817779268f);
  return 2.0f * __builtin_amdgcn_rcpf(1.0f + e) - 1.0f;
}

// fp32 -> fp16 convert, 4 elems/thread
__global__ void cvt_f32_f16(const float* __restrict__ in, f16* __restrict__ out, int n4) {
  int i = blockIdx.x * blockDim.x + threadIdx.x;
  if (i < n4) {
    float4 v = ((const float4*)in)[i];
    f16x4 o;
    o[0] = (f16)v.x; o[1] = (f16)v.y; o[2] = (f16)v.z; o[3] = (f16)v.w;
    ((f16x4*)out)[i] = o;
  }
}

// load one MFMA B-fragment (8 contiguous k) from fp32 weight row, converting to f16
__device__ __forceinline__ f16x8 load_wfrag(const float* __restrict__ W, int n, int stride, int k) {
  const float* p = W + (size_t)n * stride + k;
  float4 a = *(const float4*)p;
  float4 b = *(const float4*)(p + 4);
  f16x8 r;
  r[0] = (f16)a.x; r[1] = (f16)a.y; r[2] = (f16)a.z; r[3] = (f16)a.w;
  r[4] = (f16)b.x; r[5] = (f16)b.y; r[6] = (f16)b.z; r[7] = (f16)b.w;
  return r;
}

// Layer-0 BiLSTM scan, input projection fused (K=64). One block = 16 batches,
// all T steps. 512 thr / 8 waves; wave w owns gate cols [64w, 64w+64).
// blocks 0..15 forward, 16..31 reverse. Writes hs[b][t][dir*128+j] (f16).
__global__ __launch_bounds__(512, 1) void lstm_scan_l0(
    const f16* __restrict__ xf,
    const float* __restrict__ Wih_f, const float* __restrict__ Whh_f,
    const float* __restrict__ bih_f, const float* __restrict__ bhh_f,
    const float* __restrict__ Wih_r, const float* __restrict__ Whh_r,
    const float* __restrict__ bih_r, const float* __restrict__ bhh_r,
    f16* __restrict__ hs) {
  const int dir = ((int)blockIdx.x >= 16) ? 1 : 0;
  const int bb = ((int)blockIdx.x & 15) * 16;
  const float* __restrict__ Wih = dir ? Wih_r : Wih_f;
  const float* __restrict__ Whh = dir ? Whh_r : Whh_f;
  const float* __restrict__ bih = dir ? bih_r : bih_f;
  const float* __restrict__ bhh = dir ? bhh_r : bhh_f;

  __shared__ float act[16][516];                 // stride 516: bank rotation
  __shared__ __align__(16) f16 hq[16][136];      // h state, A-frag staging

  const int tid = threadIdx.x;
  const int lane = tid & 63;
  const int w = tid >> 6;
  const int l15 = lane & 15;
  const int q = lane >> 4;
  const int gbase = w * 64;
  const bool is_tanh_w = (w >> 1) == 2;          // cols 256..383 = g gate

  // W fragments (fp32 -> f16 once): B[k][n]=W[n][k], n=gbase+nt*16+l15, k=kt*32+q*8+j
  f16x8 wi[4][2], wh[4][4];
#pragma unroll
  for (int nt = 0; nt < 4; ++nt) {
    const int n = gbase + nt * 16 + l15;
#pragma unroll
    for (int kt = 0; kt < 2; ++kt) wi[nt][kt] = load_wfrag(Wih, n, Isz, kt * 32 + q * 8);
#pragma unroll
    for (int kt = 0; kt < 4; ++kt) wh[nt][kt] = load_wfrag(Whh, n, Hsz, kt * 32 + q * 8);
  }
  float bsum[4];
#pragma unroll
  for (int nt = 0; nt < 4; ++nt) {
    const int n = gbase + nt * 16 + l15;
    bsum[nt] = bih[n] + bhh[n];
  }

  for (int i = tid; i < 16 * 136; i += 512) (&hq[0][0])[i] = (f16)0.f;

  float cst[4] = {0.f, 0.f, 0.f, 0.f};
  const int j = tid & 127;
  const int mq = tid >> 7;

  const int t0 = dir ? (Tsz - 1) : 0;
  const int dt = dir ? -1 : 1;

  // x A-frags: row bb+l15, k = kt*32 + q*8
  const f16* xp = xf + ((size_t)(bb + l15) * Tsz + t0) * Isz + q * 8;
  const ptrdiff_t xstep = (ptrdiff_t)dt * Isz;
  f16x8 xa0 = *(const f16x8*)xp;
  f16x8 xa1 = *(const f16x8*)(xp + 32);
  xp += xstep;

  __syncthreads();

  int t_x = t0;
  for (int t = 0; t < Tsz; ++t) {
    // prefetch next x early (full step of latency)
    f16x8 xn0, xn1;
    const bool more = (t + 1 < Tsz);
    if (more) {
      xn0 = *(const f16x8*)xp;
      xn1 = *(const f16x8*)(xp + 32);
      xp += xstep;
    }

    f16x8 ah[4];
#pragma unroll
    for (int kt = 0; kt < 4; ++kt)
      ah[kt] = *(const f16x8*)(&hq[l15][kt * 32 + q * 8]);

    floatx4 acc[4];
#pragma unroll
    for (int nt = 0; nt < 4; ++nt) {
      acc[nt][0] = bsum[nt]; acc[nt][1] = bsum[nt];
      acc[nt][2] = bsum[nt]; acc[nt][3] = bsum[nt];
    }
#pragma unroll
    for (int nt = 0; nt < 4; ++nt) acc[nt] = MFMA(xa0, wi[nt][0], acc[nt]);
#pragma unroll
    for (int nt = 0; nt < 4; ++nt) acc[nt] = MFMA(xa1, wi[nt][1], acc[nt]);
#pragma unroll
    for (int kt = 0; kt < 4; ++kt)
#pragma unroll
      for (int nt = 0; nt < 4; ++nt) acc[nt] = MFMA(ah[kt], wh[nt][kt], acc[nt]);

    // activations -> act LDS (wave-uniform activation type)
    if (is_tanh_w) {
#pragma unroll
      for (int nt = 0; nt < 4; ++nt) {
        const int n = gbase + nt * 16 + l15;
#pragma unroll
        for (int r = 0; r < 4; ++r) act[4 * q + r][n] = tanh_f(acc[nt][r]);
      }
    } else {
#pragma unroll
      for (int nt = 0; nt < 4; ++nt) {
        const int n = gbase + nt * 16 + l15;
#pragma unroll
        for (int r = 0; r < 4; ++r) act[4 * q + r][n] = sigm_f(acc[nt][r]);
      }
    }
    __syncthreads();

#pragma unroll
    for (int r = 0; r < 4; ++r) {
      const int m = mq * 4 + r;
      const float ia = act[m][j];
      const float fa = act[m][128 + j];
      const float ga = act[m][256 + j];
      const float oa = act[m][384 + j];
      const float c = fa * cst[r] + ia * ga;
      cst[r] = c;
      const float h = oa * tanh_f(c);
      const f16 hf = (f16)h;
      hq[m][j] = hf;
      hs[((size_t)(bb + m) * Tsz + t_x) * 256 + dir * 128 + j] = hf;
    }
    __syncthreads();

    xa0 = xn0; xa1 = xn1;
    t_x += dt;
  }
}

// Layer-1 forward scan, input projection (K=256 over hs) fused. 16 blocks.
// hs rows staged per-step through an LDS double buffer (reg round-trip).
__global__ __launch_bounds__(512, 1) void lstm_scan_l1(
    const f16* __restrict__ hs,
    const float* __restrict__ Wih, const float* __restrict__ Whh,
    const float* __restrict__ bih, const float* __restrict__ bhh,
    float* __restrict__ hfinal) {
  const int bb = (int)blockIdx.x * 16;

  __shared__ float act[16][516];
  __shared__ __align__(16) f16 hq[16][136];
  __shared__ __align__(16) f16 xq[2][16][264];   // staged hs rows, stride 264

  const int tid = threadIdx.x;
  const int lane = tid & 63;
  const int w = tid >> 6;
  const int l15 = lane & 15;
  const int q = lane >> 4;
  const int gbase = w * 64;
  const bool is_tanh_w = (w >> 1) == 2;

  f16x8 wi[4][8], wh[4][4];
#pragma unroll
  for (int nt = 0; nt < 4; ++nt) {
    const int n = gbase + nt * 16 + l15;
#pragma unroll
    for (int kt = 0; kt < 8; ++kt) wi[nt][kt] = load_wfrag(Wih, n, 256, kt * 32 + q * 8);
#pragma unroll
    for (int kt = 0; kt < 4; ++kt) wh[nt][kt] = load_wfrag(Whh, n, Hsz, kt * 32 + q * 8);
  }
  float bsum[4];
#pragma unroll
  for (int nt = 0; nt < 4; ++nt) {
    const int n = gbase + nt * 16 + l15;
    bsum[nt] = bih[n] + bhh[n];
  }

  for (int i = tid; i < 16 * 136; i += 512) (&hq[0][0])[i] = (f16)0.f;

  float cst[4] = {0.f, 0.f, 0.f, 0.f};
  const int j = tid & 127;
  const int mq = tid >> 7;

  // staging role: thread -> (row sm, 16B chunk sc)
  const int sm = tid >> 5;
  const int sc = tid & 31;
  const f16* sp = hs + (size_t)(bb + sm) * Tsz * 256 + sc * 8;

  // prime t=0 into xq[0]; prefetch t=1 into reg
  f16x8 ld = *(const f16x8*)sp;
  *(f16x8*)(&xq[0][sm][sc * 8]) = ld;
  ld = *(const f16x8*)(sp + 256);
  __syncthreads();

  for (int t = 0; t < Tsz; ++t) {
    f16x8 ah[4];
#pragma unroll
    for (int kt = 0; kt < 4; ++kt)
      ah[kt] = *(const f16x8*)(&hq[l15][kt * 32 + q * 8]);

    floatx4 acc[4];
#pragma unroll
    for (int nt = 0; nt < 4; ++nt) {
      acc[nt][0] = bsum[nt]; acc[nt][1] = bsum[nt];
      acc[nt][2] = bsum[nt]; acc[nt][3] = bsum[nt];
    }
    const f16* xrow = &xq[t & 1][l15][0];
#pragma unroll
    for (int kt = 0; kt < 8; ++kt) {
      f16x8 xa = *(const f16x8*)(xrow + kt * 32 + q * 8);
#pragma unroll
      for (int nt = 0; nt < 4; ++nt) acc[nt] = MFMA(xa, wi[nt][kt], acc[nt]);
    }
#pragma unroll
    for (int kt = 0; kt < 4; ++kt)
#pragma unroll
      for (int nt = 0; nt < 4; ++nt) acc[nt] = MFMA(ah[kt], wh[nt][kt], acc[nt]);

    // publish staged row for t+1, prefetch t+2
    if (t + 1 < Tsz) {
      *(f16x8*)(&xq[(t + 1) & 1][sm][sc * 8]) = ld;
      if (t + 2 < Tsz) ld = *(const f16x8*)(sp + (size_t)(t + 2) * 256);
    }

    if (is_tanh_w) {
#pragma unroll
      for (int nt = 0; nt < 4; ++nt) {
        const int n = gbase + nt * 16 + l15;
#pragma unroll
        for (int r = 0; r < 4; ++r) act[4 * q + r][n] = tanh_f(acc[nt][r]);
      }
    } else {
#pragma unroll
      for (int nt = 0; nt < 4; ++nt) {
        const int n = gbase + nt * 16 + l15;
#pragma unroll
        for (int r = 0; r < 4; ++r) act[4 * q + r][n] = sigm_f(acc[nt][r]);
      }
    }
    __syncthreads();

#pragma unroll
    for (int r = 0; r < 4; ++r) {
      const int m = mq * 4 + r;
      const float ia = act[m][j];
      const float fa = act[m][128 + j];
      const float ga = act[m][256 + j];
      const float oa = act[m][384 + j];
      const float c = fa * cst[r] + ia * ga;
      cst[r] = c;
      const float h = oa * tanh_f(c);
      hq[m][j] = (f16)h;
      if (t == Tsz - 1) hfinal[(size_t)(bb + m) * Hsz + j] = h;
    }
    __syncthreads();
  }
}

// L1-reverse single step (h0=c0=0 -> Whh term vanishes) + FC head. 1 block/batch.
__global__ __launch_bounds__(512) void tail_kernel(
    const f16* __restrict__ hs, const float* __restrict__ hfinal,
    const float* __restrict__ Wr, const float* __restrict__ br1,
    const float* __restrict__ br2, const float* __restrict__ fc1w,
    const float* __restrict__ fc1b, const float* __restrict__ fc2w,
    const float* __restrict__ fc2b, float* __restrict__ out) {
  const int b = blockIdx.x;
  const int tid = threadIdx.x;
  __shared__ float hrow[256];
  __shared__ float gact[512];
  __shared__ float last[256];
  __shared__ float hid[128];
  __shared__ float psum[128];

  const size_t row = ((size_t)b * Tsz + (Tsz - 1)) * 256;
  if (tid < 256) hrow[tid] = (float)hs[row + tid];
  __syncthreads();

  {
    float a = br1[tid] + br2[tid];
    const float* wr = Wr + (size_t)tid * 256;
#pragma unroll 8
    for (int k = 0; k < 256; ++k) a += hrow[k] * wr[k];
    gact[tid] = (tid >= 256 && tid < 384) ? tanh_f(a) : sigm_f(a);
  }
  __syncthreads();

  if (tid < 128) {
    const float c = gact[tid] * gact[256 + tid];      // sig(i)*tanh(g), c0=0
    const float hb = gact[384 + tid] * tanh_f(c);
    last[tid] = hfinal[(size_t)b * Hsz + tid];
    last[128 + tid] = hb;
  }
  __syncthreads();

  if (tid < 128) {
    float a = fc1b[tid];
    const float* w1 = fc1w + (size_t)tid * 256;
#pragma unroll 8
    for (int k = 0; k < 256; ++k) a += last[k] * w1[k];
    hid[tid] = fmaxf(a, 0.f);
  }
  __syncthreads();
  if (tid < 128) psum[tid] = hid[tid] * fc2w[tid];
  __syncthreads();
  if (tid == 0) {
    float s = fc2b[0];
    for (int k = 0; k < 128; ++k) s += psum[k];
    out[b] = s;
  }
}

extern "C" void kernel_launch(void* const* d_in, const int* in_sizes, int n_in,
                              void* d_out, int out_size, void* d_ws, size_t ws_size,
                              hipStream_t stream) {
  (void)in_sizes; (void)n_in; (void)out_size;
  const float* x = (const float*)d_in[0];
  const float* Wih_l0 = (const float*)d_in[1];
  const float* Whh_l0 = (const float*)d_in[2];
  const float* bih_l0 = (const float*)d_in[3];
  const float* bhh_l0 = (const float*)d_in[4];
  const float* Wih_l0r = (const float*)d_in[5];
  const float* Whh_l0r = (const float*)d_in[6];
  const float* bih_l0r = (const float*)d_in[7];
  const float* bhh_l0r = (const float*)d_in[8];
  const float* Wih_l1 = (const float*)d_in[9];
  const float* Whh_l1 = (const float*)d_in[10];
  const float* bih_l1 = (const float*)d_in[11];
  const float* bhh_l1 = (const float*)d_in[12];
  const float* Wih_l1r = (const float*)d_in[13];
  // d_in[14] = W_hh_l1r unused (reverse h0 = 0)
  const float* bih_l1r = (const float*)d_in[15];
  const float* bhh_l1r = (const float*)d_in[16];
  const float* fc1w = (const float*)d_in[17];
  const float* fc1b = (const float*)d_in[18];
  const float* fc2w = (const float*)d_in[19];
  const float* fc2b = (const float*)d_in[20];
  float* out = (float*)d_out;

  char* ws = (char*)d_ws;
  const size_t M = (size_t)Bsz * Tsz;        // 131072
  const size_t XFB = M * Isz * 2;            // 16.8 MB  x in f16
  const size_t HSB = M * 256 * 2;            // 67.1 MB  hs in f16
  const size_t HFB = (size_t)Bsz * Hsz * 4;  // 131 KB   L1 fwd final h
  const size_t need = XFB + HSB + HFB;
  if (ws_size < need) return;  // ws-theory probe: fail clean (absmax), not fault

  size_t off = 0;
  f16* xf = (f16*)(ws + off); off += XFB;
  f16* hsb = (f16*)(ws + off); off += HSB;
  float* hfinal = (float*)(ws + off); off += HFB;

  const int n4 = (int)(M * Isz / 4);
  cvt_f32_f16<<<dim3((n4 + 255) / 256), dim3(256), 0, stream>>>(x, xf, n4);

  lstm_scan_l0<<<dim3(32), dim3(512), 0, stream>>>(
      xf, Wih_l0, Whh_l0, bih_l0, bhh_l0, Wih_l0r, Whh_l0r, bih_l0r, bhh_l0r, hsb);

  lstm_scan_l1<<<dim3(16), dim3(512), 0, stream>>>(
      hsb, Wih_l1, Whh_l1, bih_l1, bhh_l1, hfinal);

  tail_kernel<<<dim3(256), dim3(512), 0, stream>>>(
      hsb, hfinal, Wih_l1r, bih_l1r, bhh_l1r, fc1w, fc1b, fc2w, fc2b, out);
}

// Round 3
// 1252.246 us; speedup vs baseline: 1.3050x; 1.3050x over previous
//
#include <hip/hip_runtime.h>

#define Bsz 256
#define Tsz 512
#define Isz 64
#define Hsz 128
#define G4  512   // 4*H

typedef _Float16 f16;
typedef _Float16 f16x8 __attribute__((ext_vector_type(8)));
typedef _Float16 f16x4 __attribute__((ext_vector_type(4)));
typedef float floatx4 __attribute__((ext_vector_type(4)));

#define MFMA(A, B, C) __builtin_amdgcn_mfma_f32_16x16x32_f16((A), (B), (C), 0, 0, 0)

__device__ __forceinline__ float sigm_f(float x) {
  float e = __builtin_amdgcn_exp2f(x * -1.4426950408889634f);
  return __builtin_amdgcn_rcpf(1.0f + e);
}
__device__ __forceinline__ float tanh_f(float x) {
  float e = __builtin_amdgcn_exp2f(x * -2.8853900817779268f);
  return 2.0f * __builtin_amdgcn_rcpf(1.0f + e) - 1.0f;
}

// fp32 -> fp16 convert, 4 elems/thread
__global__ void cvt_f32_f16(const float* __restrict__ in, f16* __restrict__ out, int n4) {
  int i = blockIdx.x * blockDim.x + threadIdx.x;
  if (i < n4) {
    float4 v = ((const float4*)in)[i];
    f16x4 o;
    o[0] = (f16)v.x; o[1] = (f16)v.y; o[2] = (f16)v.z; o[3] = (f16)v.w;
    ((f16x4*)out)[i] = o;
  }
}

// load one MFMA B-fragment (8 contiguous k) from fp32 weight row, converting to f16
__device__ __forceinline__ f16x8 load_wfrag(const float* __restrict__ W, int n, int stride, int k) {
  const float* p = W + (size_t)n * stride + k;
  float4 a = *(const float4*)p;
  float4 b = *(const float4*)(p + 4);
  f16x8 r;
  r[0] = (f16)a.x; r[1] = (f16)a.y; r[2] = (f16)a.z; r[3] = (f16)a.w;
  r[4] = (f16)b.x; r[5] = (f16)b.y; r[6] = (f16)b.z; r[7] = (f16)b.w;
  return r;
}

// Layer-0 BiLSTM scan, input projection fused (K=64). One block = 16 batches,
// all T steps. 512 thr / 8 waves. Wave w owns j-slice [16w,16w+16) of ALL 4
// gates (n-tiles g*128+16w, g=0..3): i/f/g/o for one (m,j) land in ONE lane
// (D-layout col=lane&15, row=4q+r) -> in-register cell update, no gate LDS
// exchange. h double-buffered in LDS -> ONE barrier per step.
// blocks 0..15 forward, 16..31 reverse. Writes hs[b][t][dir*128+j] (f16).
__global__ __launch_bounds__(512, 1) void lstm_scan_l0(
    const f16* __restrict__ xf,
    const float* __restrict__ Wih_f, const float* __restrict__ Whh_f,
    const float* __restrict__ bih_f, const float* __restrict__ bhh_f,
    const float* __restrict__ Wih_r, const float* __restrict__ Whh_r,
    const float* __restrict__ bih_r, const float* __restrict__ bhh_r,
    f16* __restrict__ hs) {
  const int dir = ((int)blockIdx.x >= 16) ? 1 : 0;
  const int bb = ((int)blockIdx.x & 15) * 16;
  const float* __restrict__ Wih = dir ? Wih_r : Wih_f;
  const float* __restrict__ Whh = dir ? Whh_r : Whh_f;
  const float* __restrict__ bih = dir ? bih_r : bih_f;
  const float* __restrict__ bhh = dir ? bhh_r : bhh_f;

  __shared__ __align__(16) f16 hq[2][16][136];   // h state, double-buffered A-frag staging

  const int tid = threadIdx.x;
  const int lane = tid & 63;
  const int w = tid >> 6;
  const int l15 = lane & 15;
  const int q = lane >> 4;
  const int jb = w * 16;          // j-slice base
  const int jcol = jb + l15;      // this lane's hidden index

  // W fragments: gate g cols n = g*128 + jcol; B[k][n]=W[n][k], k = kt*32+q*8+jj
  f16x8 wi[4][2], wh[4][4];
  float bsum[4];
#pragma unroll
  for (int g = 0; g < 4; ++g) {
    const int n = g * 128 + jcol;
#pragma unroll
    for (int kt = 0; kt < 2; ++kt) wi[g][kt] = load_wfrag(Wih, n, Isz, kt * 32 + q * 8);
#pragma unroll
    for (int kt = 0; kt < 4; ++kt) wh[g][kt] = load_wfrag(Whh, n, Hsz, kt * 32 + q * 8);
    bsum[g] = bih[n] + bhh[n];
  }

  for (int i = tid; i < 16 * 136; i += 512) (&hq[0][0][0])[i] = (f16)0.f;

  float cst[4] = {0.f, 0.f, 0.f, 0.f};  // c[m=4q+r][jcol]

  const int t0 = dir ? (Tsz - 1) : 0;
  const int dt = dir ? -1 : 1;

  // x A-frags: row bb+l15, k = kt*32 + q*8 (all waves load same rows; L1 absorbs)
  const f16* xp = xf + ((size_t)(bb + l15) * Tsz + t0) * Isz + q * 8;
  const ptrdiff_t xstep = (ptrdiff_t)dt * Isz;
  f16x8 xa0 = *(const f16x8*)xp;
  f16x8 xa1 = *(const f16x8*)(xp + 32);
  xp += xstep;

  // hs store base for this lane: rows m=4q+r, col dir*128+jcol
  f16* hsp = hs + ((size_t)(bb + 4 * q) * Tsz + t0) * 256 + dir * 128 + jcol;
  const ptrdiff_t hstep = (ptrdiff_t)dt * 256;

  __syncthreads();

  for (int t = 0; t < Tsz; ++t) {
    // prefetch next x (independent, a full step of latency)
    f16x8 xn0, xn1;
    if (t + 1 < Tsz) {
      xn0 = *(const f16x8*)xp;
      xn1 = *(const f16x8*)(xp + 32);
      xp += xstep;
    }

    // h_{t-1} A-frags from LDS (buffer t&1)
    f16x8 ah[4];
#pragma unroll
    for (int kt = 0; kt < 4; ++kt)
      ah[kt] = *(const f16x8*)(&hq[t & 1][l15][kt * 32 + q * 8]);

    floatx4 acc[4];
#pragma unroll
    for (int g = 0; g < 4; ++g) {
      acc[g][0] = bsum[g]; acc[g][1] = bsum[g];
      acc[g][2] = bsum[g]; acc[g][3] = bsum[g];
    }
    // x projection (h-independent; issues under the ds_read latency)
#pragma unroll
    for (int g = 0; g < 4; ++g) acc[g] = MFMA(xa0, wi[g][0], acc[g]);
#pragma unroll
    for (int g = 0; g < 4; ++g) acc[g] = MFMA(xa1, wi[g][1], acc[g]);
    // recurrent part: 4-deep dependent chain, 4 independent g-chains
#pragma unroll
    for (int kt = 0; kt < 4; ++kt)
#pragma unroll
      for (int g = 0; g < 4; ++g) acc[g] = MFMA(ah[kt], wh[g][kt], acc[g]);

    // in-register cell update; write h to other hq buffer + global hs
#pragma unroll
    for (int r = 0; r < 4; ++r) {
      const float ia = sigm_f(acc[0][r]);
      const float fa = sigm_f(acc[1][r]);
      const float ga = tanh_f(acc[2][r]);
      const float oa = sigm_f(acc[3][r]);
      const float c = fa * cst[r] + ia * ga;
      cst[r] = c;
      const float h = oa * tanh_f(c);
      const f16 hf = (f16)h;
      hq[(t + 1) & 1][4 * q + r][jcol] = hf;
      hsp[(size_t)r * Tsz * 256] = hf;
    }
    hsp += hstep;
    xa0 = xn0; xa1 = xn1;
    __syncthreads();
  }
}

// Layer-1 forward scan, input projection (K=256 over hs) fused. 16 blocks.
// Same wave-owns-j-slice layout; hs rows staged via LDS double buffer.
__global__ __launch_bounds__(512, 1) void lstm_scan_l1(
    const f16* __restrict__ hs,
    const float* __restrict__ Wih, const float* __restrict__ Whh,
    const float* __restrict__ bih, const float* __restrict__ bhh,
    float* __restrict__ hfinal) {
  const int bb = (int)blockIdx.x * 16;

  __shared__ __align__(16) f16 hq[2][16][136];
  __shared__ __align__(16) f16 xq[2][16][264];   // staged hs rows, stride 264

  const int tid = threadIdx.x;
  const int lane = tid & 63;
  const int w = tid >> 6;
  const int l15 = lane & 15;
  const int q = lane >> 4;
  const int jb = w * 16;
  const int jcol = jb + l15;

  f16x8 wi[4][8], wh[4][4];
  float bsum[4];
#pragma unroll
  for (int g = 0; g < 4; ++g) {
    const int n = g * 128 + jcol;
#pragma unroll
    for (int kt = 0; kt < 8; ++kt) wi[g][kt] = load_wfrag(Wih, n, 256, kt * 32 + q * 8);
#pragma unroll
    for (int kt = 0; kt < 4; ++kt) wh[g][kt] = load_wfrag(Whh, n, Hsz, kt * 32 + q * 8);
    bsum[g] = bih[n] + bhh[n];
  }

  for (int i = tid; i < 16 * 136; i += 512) (&hq[0][0][0])[i] = (f16)0.f;

  float cst[4] = {0.f, 0.f, 0.f, 0.f};

  // staging role: thread -> (row sm, 16B chunk sc)
  const int sm = tid >> 5;
  const int sc = tid & 31;
  const f16* sp = hs + (size_t)(bb + sm) * Tsz * 256 + sc * 8;

  // prime t=0 into xq[0]; prefetch t=1 into reg
  f16x8 ld = *(const f16x8*)sp;
  *(f16x8*)(&xq[0][sm][sc * 8]) = ld;
  ld = *(const f16x8*)(sp + 256);
  __syncthreads();

  for (int t = 0; t < Tsz; ++t) {
    f16x8 ah[4];
#pragma unroll
    for (int kt = 0; kt < 4; ++kt)
      ah[kt] = *(const f16x8*)(&hq[t & 1][l15][kt * 32 + q * 8]);

    floatx4 acc[4];
#pragma unroll
    for (int g = 0; g < 4; ++g) {
      acc[g][0] = bsum[g]; acc[g][1] = bsum[g];
      acc[g][2] = bsum[g]; acc[g][3] = bsum[g];
    }
    const f16* xrow = &xq[t & 1][l15][0];
#pragma unroll
    for (int kt = 0; kt < 8; ++kt) {
      f16x8 xa = *(const f16x8*)(xrow + kt * 32 + q * 8);
#pragma unroll
      for (int g = 0; g < 4; ++g) acc[g] = MFMA(xa, wi[g][kt], acc[g]);
    }
#pragma unroll
    for (int kt = 0; kt < 4; ++kt)
#pragma unroll
      for (int g = 0; g < 4; ++g) acc[g] = MFMA(ah[kt], wh[g][kt], acc[g]);

    // publish staged row t+1, prefetch row t+2
    if (t + 1 < Tsz) {
      *(f16x8*)(&xq[(t + 1) & 1][sm][sc * 8]) = ld;
      if (t + 2 < Tsz) ld = *(const f16x8*)(sp + (size_t)(t + 2) * 256);
    }

#pragma unroll
    for (int r = 0; r < 4; ++r) {
      const float ia = sigm_f(acc[0][r]);
      const float fa = sigm_f(acc[1][r]);
      const float ga = tanh_f(acc[2][r]);
      const float oa = sigm_f(acc[3][r]);
      const float c = fa * cst[r] + ia * ga;
      cst[r] = c;
      const float h = oa * tanh_f(c);
      hq[(t + 1) & 1][4 * q + r][jcol] = (f16)h;
      if (t == Tsz - 1) hfinal[(size_t)(bb + 4 * q + r) * Hsz + jcol] = h;
    }
    __syncthreads();
  }
}

// L1-reverse single step (h0=c0=0 -> Whh term vanishes) + FC head. 1 block/batch.
__global__ __launch_bounds__(512) void tail_kernel(
    const f16* __restrict__ hs, const float* __restrict__ hfinal,
    const float* __restrict__ Wr, const float* __restrict__ br1,
    const float* __restrict__ br2, const float* __restrict__ fc1w,
    const float* __restrict__ fc1b, const float* __restrict__ fc2w,
    const float* __restrict__ fc2b, float* __restrict__ out) {
  const int b = blockIdx.x;
  const int tid = threadIdx.x;
  __shared__ float hrow[256];
  __shared__ float gact[512];
  __shared__ float last[256];
  __shared__ float hid[128];
  __shared__ float psum[128];

  const size_t row = ((size_t)b * Tsz + (Tsz - 1)) * 256;
  if (tid < 256) hrow[tid] = (float)hs[row + tid];
  __syncthreads();

  {
    float a = br1[tid] + br2[tid];
    const float* wr = Wr + (size_t)tid * 256;
#pragma unroll 8
    for (int k = 0; k < 256; ++k) a += hrow[k] * wr[k];
    gact[tid] = (tid >= 256 && tid < 384) ? tanh_f(a) : sigm_f(a);
  }
  __syncthreads();

  if (tid < 128) {
    const float c = gact[tid] * gact[256 + tid];      // sig(i)*tanh(g), c0=0
    const float hb = gact[384 + tid] * tanh_f(c);
    last[tid] = hfinal[(size_t)b * Hsz + tid];
    last[128 + tid] = hb;
  }
  __syncthreads();

  if (tid < 128) {
    float a = fc1b[tid];
    const float* w1 = fc1w + (size_t)tid * 256;
#pragma unroll 8
    for (int k = 0; k < 256; ++k) a += last[k] * w1[k];
    hid[tid] = fmaxf(a, 0.f);
  }
  __syncthreads();
  if (tid < 128) psum[tid] = hid[tid] * fc2w[tid];
  __syncthreads();
  if (tid == 0) {
    float s = fc2b[0];
    for (int k = 0; k < 128; ++k) s += psum[k];
    out[b] = s;
  }
}

extern "C" void kernel_launch(void* const* d_in, const int* in_sizes, int n_in,
                              void* d_out, int out_size, void* d_ws, size_t ws_size,
                              hipStream_t stream) {
  (void)in_sizes; (void)n_in; (void)out_size;
  const float* x = (const float*)d_in[0];
  const float* Wih_l0 = (const float*)d_in[1];
  const float* Whh_l0 = (const float*)d_in[2];
  const float* bih_l0 = (const float*)d_in[3];
  const float* bhh_l0 = (const float*)d_in[4];
  const float* Wih_l0r = (const float*)d_in[5];
  const float* Whh_l0r = (const float*)d_in[6];
  const float* bih_l0r = (const float*)d_in[7];
  const float* bhh_l0r = (const float*)d_in[8];
  const float* Wih_l1 = (const float*)d_in[9];
  const float* Whh_l1 = (const float*)d_in[10];
  const float* bih_l1 = (const float*)d_in[11];
  const float* bhh_l1 = (const float*)d_in[12];
  const float* Wih_l1r = (const float*)d_in[13];
  // d_in[14] = W_hh_l1r unused (reverse h0 = 0)
  const float* bih_l1r = (const float*)d_in[15];
  const float* bhh_l1r = (const float*)d_in[16];
  const float* fc1w = (const float*)d_in[17];
  const float* fc1b = (const float*)d_in[18];
  const float* fc2w = (const float*)d_in[19];
  const float* fc2b = (const float*)d_in[20];
  float* out = (float*)d_out;

  char* ws = (char*)d_ws;
  const size_t M = (size_t)Bsz * Tsz;        // 131072
  const size_t XFB = M * Isz * 2;            // 16.8 MB  x in f16
  const size_t HSB = M * 256 * 2;            // 67.1 MB  hs in f16
  const size_t HFB = (size_t)Bsz * Hsz * 4;  // 131 KB   L1 fwd final h
  const size_t need = XFB + HSB + HFB;
  if (ws_size < need) return;  // fail clean (absmax), not fault

  size_t off = 0;
  f16* xf = (f16*)(ws + off); off += XFB;
  f16* hsb = (f16*)(ws + off); off += HSB;
  float* hfinal = (float*)(ws + off); off += HFB;

  const int n4 = (int)(M * Isz / 4);
  cvt_f32_f16<<<dim3((n4 + 255) / 256), dim3(256), 0, stream>>>(x, xf, n4);

  lstm_scan_l0<<<dim3(32), dim3(512), 0, stream>>>(
      xf, Wih_l0, Whh_l0, bih_l0, bhh_l0, Wih_l0r, Whh_l0r, bih_l0r, bhh_l0r, hsb);

  lstm_scan_l1<<<dim3(16), dim3(512), 0, stream>>>(
      hsb, Wih_l1, Whh_l1, bih_l1, bhh_l1, hfinal);

  tail_kernel<<<dim3(256), dim3(512), 0, stream>>>(
      hsb, hfinal, Wih_l1r, bih_l1r, bhh_l1r, fc1w, fc1b, fc2w, fc2b, out);
}